// Round 1
// baseline (92.673 us; speedup 1.0000x reference)
//
#include <hip/hip_runtime.h>
#include <hip/hip_bf16.h>
#include <math.h>

// Batch-hard triplet loss, B=8192, D=128, fp32 in.
// dist^2[i,j] = rowterm[i] + colterm[j] - 2*dot(e1[i], e2[j])
// sqrt & max/min commute -> track max/min of (colterm - 2*dot); dot on bf16
// matrix cores. Target folded into cpos/cneg (finite +-1e30 sentinels).
//
// R8 vs R7: (1) A fragments load straight from global (e1b is 2 MB, L2-
// resident; 16 rows x 64 B per dwordx4 — fine for L2) -> As LDS buffer freed.
// (2) Bs double-buffered in the SAME 67.6 KB footprint; stage(t+1) issued at
// the TOP of iter t, single __syncthreads per tile at the bottom. R7 staged
// after compute and drained immediately -> full L2->LDS latency (~1k+ cyc)
// exposed on every tile. Now the vmcnt(0) drain sits ~2k cyc after issue.
// (3) -2 folded into e1b at prep (bf16(-2x) == -2*bf16(x) exactly) and the
// epilogue pairs into v_max3/v_min3: 256 -> 192 VALU ops/tile/wave.
// add(acc,cp) with pre-scaled acc is bit-identical to fmaf(-2,d,cp); max is
// associative -> numerics unchanged vs R7 (absmax 0).

#define DDIM   128
#define SPLITS 8
#define MARGIN 0.2f
#define EPS    1e-6f
#define SENT   1e30f

#define CHUNK_PITCH 1056           // 1024 B data + 32 B pad
#define WAVE_SPAN   (8 * CHUNK_PITCH)     // 8 chunks (32 rows) per wave
#define TILE_BYTES  (4 * WAVE_SPAN)       // 33792 B per 128x128 bf16 tile

typedef unsigned short ushort_t;
typedef __attribute__((ext_vector_type(8))) short short8;
typedef __attribute__((ext_vector_type(4))) float f32x4;

__device__ __forceinline__ ushort_t f2bf(float f) {   // fp32 -> bf16 RNE
    unsigned int u = __float_as_uint(f);
    u = (u + 0x7FFFu + ((u >> 16) & 1u)) >> 16;
    return (ushort_t)u;
}

__device__ __forceinline__ void g2lds16(const ushort_t* g, void* lds) {
    // wave-uniform lds base; lane i's 16 B land at lds + i*16
    __builtin_amdgcn_global_load_lds(
        (const __attribute__((address_space(1))) unsigned int*)g,
        (__attribute__((address_space(3))) unsigned int*)lds,
        16, 0, 0);
}

// ---- kernel 1: bf16 convert + exact fp32 row stats + zero accumulators ----
// e1b now stores bf16(-2 * e1): exact scaling (exp+1, sign flip), so the
// MFMA directly produces -2*dot and the epilogue is add+max instead of fma+max.
__global__ void prep_kernel(const float* __restrict__ e1, const float* __restrict__ e2,
                            const int* __restrict__ target,
                            ushort_t* __restrict__ e1b, ushort_t* __restrict__ e2b,
                            float* __restrict__ rowterm,
                            float* __restrict__ cpos, float* __restrict__ cneg,
                            float* __restrict__ redsum, int* __restrict__ ticket, int B) {
    if (blockIdx.x == 0 && threadIdx.x == 0) {
        redsum[0] = 0.f; redsum[1] = 0.f; *ticket = 0;
    }
    int w    = (blockIdx.x * blockDim.x + threadIdx.x) >> 6;
    int lane = threadIdx.x & 63;
    if (w >= 2 * B) return;
    bool first = (w < B);
    int r = first ? w : w - B;
    const float* src = (first ? e1 : e2) + (size_t)r * DDIM;
    float2 v = *(const float2*)(src + lane * 2);
    ushort_t* dst = (first ? e1b : e2b) + (size_t)r * DDIM;
    ushort2 o;
    if (first) { o.x = f2bf(-2.f * v.x); o.y = f2bf(-2.f * v.y); }
    else       { o.x = f2bf(v.x);        o.y = f2bf(v.y); }
    *(ushort2*)(dst + lane * 2) = o;
    float s = v.x + v.y;
    float n = v.x * v.x + v.y * v.y;
    #pragma unroll
    for (int off = 32; off > 0; off >>= 1) {
        s += __shfl_down(s, off, 64);
        n += __shfl_down(n, off, 64);
    }
    if (lane == 0) {
        if (first) {
            rowterm[r] = n + 2.f * EPS * s + (float)DDIM * EPS * EPS;
        } else {
            float ct = n - 2.f * EPS * s;
            int tg = target[r];
            cpos[r] = (tg == 1) ? ct : -SENT;
            cneg[r] = (tg == 0) ? ct :  SENT;
        }
    }
}

// stage a 128x128 bf16 tile via DMA: wave w -> rows [w*32, w*32+32)
__device__ __forceinline__ void stage_tile_dma(const ushort_t* __restrict__ gRow0,
                                               unsigned char* __restrict__ lds,
                                               int w, int l) {
    const ushort_t* g = gRow0 + (size_t)(w * 32) * DDIM + l * 8;
    unsigned char* lp = lds + w * WAVE_SPAN;
    #pragma unroll
    for (int it = 0; it < 8; ++it)
        g2lds16(g + it * 512, lp + it * CHUNK_PITCH);
}

// ---- kernel 2: MFMA tile + fused masked max/min -------------------------
// grid (B/128, SPLITS), block 256 = 4 waves; 128x128 tile, K=128.
// A frags from global (L2), B double-buffered in LDS, one barrier per tile.
__global__ __launch_bounds__(256, 2)
void tile_kernel(const ushort_t* __restrict__ e1b, const ushort_t* __restrict__ e2b,
                 const float* __restrict__ cpos, const float* __restrict__ cneg,
                 float* __restrict__ pmp, float* __restrict__ nmp, int B) {
    __shared__ __align__(16) unsigned char Bs[2][TILE_BYTES];   // 67584 B

    const int tid = threadIdx.x;
    const int w   = tid >> 6;
    const int l   = tid & 63;
    const int lq  = l >> 4;          // quad 0..3
    const int lm  = l & 15;
    const int row0 = blockIdx.x * 128;
    const int colSpan = B / SPLITS;                  // 1024
    const int col0 = blockIdx.y * colSpan;
    const int nTiles = colSpan / 128;                // 8

    const int wr = (w >> 1) * 64;    // wave quadrant in tile
    const int wc = (w & 1) * 64;

    // fragment row R = wc + j*16 + lm; byte addr in buffer =
    //   (R>>2)*1056 + (R&3)*256 + lq*16 + kk*2  (laneBase lane-constant)
    const unsigned char* bLane0 = Bs[0] + ((wc >> 2) + (lm >> 2)) * CHUNK_PITCH
                                        + (lm & 3) * 256 + lq * 16;

    // A fragments straight from global: row = row0+wr+i*16+lm,
    // elems [k4*32 + lq*8, +8). 16 rows x 64 B per load -> L2-friendly.
    const ushort_t* aG = e1b + (size_t)(row0 + wr + lm) * DDIM + lq * 8;
    short8 afr[4][4];                // [i][k4]
    #pragma unroll
    for (int i = 0; i < 4; ++i)
        #pragma unroll
        for (int k4 = 0; k4 < 4; ++k4)
            afr[i][k4] = *(const short8*)(aG + i * 16 * DDIM + k4 * 32);

    stage_tile_dma(e2b + (size_t)col0 * DDIM, Bs[0], w, l);

    float pm[4][4], nm[4][4];        // [i][r]: local row = wr + i*16 + lq*4 + r
    #pragma unroll
    for (int i = 0; i < 4; ++i)
        #pragma unroll
        for (int r = 0; r < 4; ++r) { pm[i][r] = -SENT; nm[i][r] = SENT; }

    __syncthreads();                 // A frags + tile 0 staged (vmcnt drain)

    for (int t = 0; t < nTiles; ++t) {
        // issue next tile's DMA FIRST; it lands under this tile's compute
        if (t + 1 < nTiles)
            stage_tile_dma(e2b + (size_t)(col0 + (t + 1) * 128) * DDIM,
                           Bs[(t + 1) & 1], w, l);

        const unsigned char* bl = bLane0 + (t & 1) * TILE_BYTES;

        f32x4 acc[4][4];
        #pragma unroll
        for (int i = 0; i < 4; ++i)
            #pragma unroll
            for (int j = 0; j < 4; ++j)
                acc[i][j] = (f32x4){0.f, 0.f, 0.f, 0.f};

        #pragma unroll
        for (int kk = 0; kk < DDIM; kk += 32) {
            const int k4 = kk >> 5;
            const int ko = kk * 2;   // byte offset within row
            short8 bf[4];
            #pragma unroll
            for (int j = 0; j < 4; ++j)
                bf[j] = *(const short8*)(bl + j * (4 * CHUNK_PITCH) + ko);
            #pragma unroll
            for (int i = 0; i < 4; ++i)
                #pragma unroll
                for (int j = 0; j < 4; ++j)
                    acc[i][j] = __builtin_amdgcn_mfma_f32_16x16x32_bf16(
                                    afr[i][k4], bf[j], acc[i][j], 0, 0, 0);
        }

        // epilogue: acc already = -2*dot. Pair j's so clang fuses v_max3/v_min3.
        {
            const int colb = col0 + t * 128 + wc + lm;   // C/D: col = lane&15
            #pragma unroll
            for (int jp = 0; jp < 2; ++jp) {
                const int j0 = 2 * jp, j1 = j0 + 1;
                const float cp0 = cpos[colb + j0 * 16], cn0 = cneg[colb + j0 * 16];
                const float cp1 = cpos[colb + j1 * 16], cn1 = cneg[colb + j1 * 16];
                #pragma unroll
                for (int i = 0; i < 4; ++i)
                    #pragma unroll
                    for (int r = 0; r < 4; ++r) {
                        const float d0 = acc[i][j0][r];
                        const float d1 = acc[i][j1][r];
                        pm[i][r] = fmaxf(fmaxf(pm[i][r], d0 + cp0), d1 + cp1);
                        nm[i][r] = fminf(fminf(nm[i][r], d0 + cn0), d1 + cn1);
                    }
            }
        }

        __syncthreads();   // drains stage(t+1) DMA; all waves done with Bs[t&1]
    }

    // intra-wave: reduce across the 16 column-lanes (rows fixed per (lq,r))
    #pragma unroll
    for (int m = 1; m < 16; m <<= 1) {
        #pragma unroll
        for (int i = 0; i < 4; ++i)
            #pragma unroll
            for (int r = 0; r < 4; ++r) {
                pm[i][r] = fmaxf(pm[i][r], __shfl_xor(pm[i][r], m, 64));
                nm[i][r] = fminf(nm[i][r], __shfl_xor(nm[i][r], m, 64));
            }
    }

    // cross-wave: waves (2h, 2h+1) share rows over complementary column
    // halves -> combine via LDS scratch (loop's last barrier already passed).
    float* smP = (float*)Bs;               // [128]
    float* smN = smP + 128;                // [128]
    if ((w & 1) == 1 && lm == 0) {
        #pragma unroll
        for (int i = 0; i < 4; ++i)
            #pragma unroll
            for (int r = 0; r < 4; ++r) {
                int lr = wr + i * 16 + lq * 4 + r;
                smP[lr] = pm[i][r];
                smN[lr] = nm[i][r];
            }
    }
    __syncthreads();
    if ((w & 1) == 0 && lm == 0) {
        #pragma unroll
        for (int i = 0; i < 4; ++i)
            #pragma unroll
            for (int r = 0; r < 4; ++r) {
                int lr  = wr + i * 16 + lq * 4 + r;     // C/D: row = quad*4+reg
                int row = row0 + lr;
                pmp[(size_t)blockIdx.y * B + row] = fmaxf(pm[i][r], smP[lr]);
                nmp[(size_t)blockIdx.y * B + row] = fminf(nm[i][r], smN[lr]);
            }
    }
}

// ---- kernel 3: per-row combine + hinge; atomic partials; last block divides ----
__global__ void reduce_kernel(const float* __restrict__ pmp, const float* __restrict__ nmp,
                              const float* __restrict__ rowterm, const int* __restrict__ target,
                              float* __restrict__ redsum, int* __restrict__ ticket,
                              float* __restrict__ out, int B) {
    int row = blockIdx.x * blockDim.x + threadIdx.x;    // 32 x 256 = 8192
    float s = 0.f, c = 0.f;
    {
        float pmv = -SENT, nmv = SENT;
        #pragma unroll
        for (int sp = 0; sp < SPLITS; ++sp) {
            pmv = fmaxf(pmv, pmp[(size_t)sp * B + row]);
            nmv = fminf(nmv, nmp[(size_t)sp * B + row]);
        }
        float rt = rowterm[row];
        float dp = sqrtf(fmaxf(rt + pmv, 0.f));
        float dn = sqrtf(fmaxf(rt + nmv, 0.f));
        if (target[row] == 1) {
            s = fmaxf(dp - dn + MARGIN, 0.f);
            c = 1.f;
        }
    }
    #pragma unroll
    for (int off = 32; off > 0; off >>= 1) {
        s += __shfl_down(s, off, 64);
        c += __shfl_down(c, off, 64);
    }
    __shared__ float ls[4], lc[4];
    int wv = threadIdx.x >> 6, ln = threadIdx.x & 63;
    if (ln == 0) { ls[wv] = s; lc[wv] = c; }
    __syncthreads();
    if (threadIdx.x == 0) {
        float ss = ls[0] + ls[1] + ls[2] + ls[3];
        float cc = lc[0] + lc[1] + lc[2] + lc[3];
        atomicAdd(&redsum[0], ss);
        atomicAdd(&redsum[1], cc);
        __threadfence();
        int done = atomicAdd(ticket, 1);
        if (done == (int)gridDim.x - 1) {
            __threadfence();
            float fs = __hip_atomic_load(&redsum[0], __ATOMIC_RELAXED, __HIP_MEMORY_SCOPE_AGENT);
            float fc = __hip_atomic_load(&redsum[1], __ATOMIC_RELAXED, __HIP_MEMORY_SCOPE_AGENT);
            out[0] = fs / fc;
        }
    }
}

extern "C" void kernel_launch(void* const* d_in, const int* in_sizes, int n_in,
                              void* d_out, int out_size, void* d_ws, size_t ws_size,
                              hipStream_t stream) {
    const float* e1     = (const float*)d_in[0];
    const float* e2     = (const float*)d_in[1];
    const int*   target = (const int*)d_in[2];
    float* out = (float*)d_out;
    const int B = in_sizes[2];                       // 8192

    // ws layout: e1b | e2b | rowterm | cpos | cneg | pmp | nmp | redsum | ticket (~4.8 MB)
    char* p = (char*)d_ws;
    ushort_t* e1b  = (ushort_t*)p;   p += (size_t)B * DDIM * 2;   // 2 MB (scaled by -2)
    ushort_t* e2b  = (ushort_t*)p;   p += (size_t)B * DDIM * 2;   // 2 MB
    float* rowterm = (float*)p;      p += (size_t)B * 4;
    float* cpos    = (float*)p;      p += (size_t)B * 4;
    float* cneg    = (float*)p;      p += (size_t)B * 4;
    float* pmp     = (float*)p;      p += (size_t)SPLITS * B * 4;
    float* nmp     = (float*)p;      p += (size_t)SPLITS * B * 4;
    float* redsum  = (float*)p;      p += 2 * 4;
    int*   ticket  = (int*)p;

    {   // prep: one wave per row, 2B rows, 4 waves/block
        int blocks = (2 * B + 3) / 4;
        prep_kernel<<<blocks, 256, 0, stream>>>(e1, e2, target, e1b, e2b,
                                                rowterm, cpos, cneg, redsum, ticket, B);
    }
    {   // 64 row-blocks x 8 col-splits = 512 blocks = 2/CU (66 KB LDS)
        dim3 grid(B / 128, SPLITS);
        tile_kernel<<<grid, 256, 0, stream>>>(e1b, e2b, cpos, cneg, pmp, nmp, B);
    }
    reduce_kernel<<<32, 256, 0, stream>>>(pmp, nmp, rowterm, target,
                                          redsum, ticket, out, B);
}